// Round 8
// baseline (228.004 us; speedup 1.0000x reference)
//
#include <hip/hip_runtime.h>
#include <hip/hip_bf16.h>

typedef unsigned short u16;
typedef unsigned int   u32;

using bf8 = __attribute__((ext_vector_type(8))) __bf16;
using f4  = __attribute__((ext_vector_type(4))) float;

__device__ __forceinline__ float b2f(u16 u) {
    union { u32 i; float f; } v; v.i = ((u32)u) << 16; return v.f;
}
__device__ __forceinline__ u16 f2b(float f) {
    union { float f; u32 i; } v; v.f = f;
    u32 x = v.i;
    x += 0x7fffu + ((x >> 16) & 1u);   // RNE
    return (u16)(x >> 16);
}
// Packed fp32x2 -> bf16x2 (low = first arg).
__device__ __forceinline__ u32 pk2(float lo, float hi) {
    union { __hip_bfloat162 h; u32 u; } v;
    v.h = __float22bfloat162_rn(make_float2(lo, hi));
    return v.u;
}

// ---------------------------------------------------------------------------
// Weight swizzle (verified layout, round-7 shape):
// dst[((kt*16+ct)*64+lane)*8+j] = bf16(W[kt*32+(lane>>4)*8+j][ct*16+(lane&15)])
// ---------------------------------------------------------------------------
__global__ void swz_all(const float* __restrict__ w1, const float* __restrict__ w3,
                        const float* __restrict__ w2, const float* __restrict__ w4,
                        const float* __restrict__ w5, const float* __restrict__ w7,
                        u16* __restrict__ ws) {
    __shared__ u16 slab[32 * 270];
    int b = blockIdx.x, t = threadIdx.x;
    const float* src; u16* dst; int kmax, kt;
    if      (b <  2) { src = w1; dst = ws;          kmax = 54;  kt = b;      }
    else if (b <  4) { src = w3; dst = ws + 16384;  kmax = 54;  kt = b - 2;  }
    else if (b < 12) { src = w2; dst = ws + 32768;  kmax = 256; kt = b - 4;  }
    else if (b < 20) { src = w4; dst = ws + 98304;  kmax = 256; kt = b - 12; }
    else if (b < 28) { src = w5; dst = ws + 163840; kmax = 256; kt = b - 20; }
    else             { src = w7; dst = ws + 229376; kmax = 256; kt = b - 28; }

    #pragma unroll
    for (int it = 0; it < 8; ++it) {
        int flat = it * 1024 + t * 4;
        int row = flat >> 8, col = flat & 255;
        int k = kt * 32 + row;
        float4 v = make_float4(0.f, 0.f, 0.f, 0.f);
        if (k < kmax) v = *(const float4*)(src + k * 256 + col);
        u32* sp = (u32*)&slab[row * 270 + col];
        sp[0] = pk2(v.x, v.y);
        sp[1] = pk2(v.z, v.w);
    }
    __syncthreads();

    int lane = t & 63, wave = t >> 6, lr = lane & 15, kg = lane >> 4;
    #pragma unroll
    for (int i = 0; i < 4; ++i) {
        int ct = wave * 4 + i;
        u16 v[8];
        #pragma unroll
        for (int j = 0; j < 8; ++j)
            v[j] = slab[(kg * 8 + j) * 270 + ct * 16 + lr];
        uint4 o;
        o.x = (u32)v[0] | ((u32)v[1] << 16);
        o.y = (u32)v[2] | ((u32)v[3] << 16);
        o.z = (u32)v[4] | ((u32)v[5] << 16);
        o.w = (u32)v[6] | ((u32)v[7] << 16);
        *(uint4*)(dst + (size_t)(((kt * 16 + ct) * 64 + lane) * 8)) = o;
    }
}

// ---------------------------------------------------------------------------
// Fused critic. One WG = 32 batch rows, 512 threads (8 waves), each wave owns
// 2 column-tiles (ct = wave*2 + c). 2 WG/CU -> 16 waves/CU (vs 8 in r7).
// LDS pool (u16): inp [0,6912) 96x72; h [6912, 6912+96*266) stride 266.
// h reuse: S1 rows 0..31, S2 rows 32..63, RH0 rows 64..95, RH1 over S1.
// MFMA mappings verified end-to-end (rounds 2/3/6).
// ---------------------------------------------------------------------------
#define HS    266
#define H_OFF 6912
#define S2O   (32 * HS)
#define RH0O  (64 * HS)

__global__ __launch_bounds__(512, 4) void critic_kernel(
    const float* __restrict__ obs, const float* __restrict__ ag,
    const float* __restrict__ g,   const float* __restrict__ anchor,
    const float* __restrict__ act,
    const float* __restrict__ b1,  const float* __restrict__ b2,
    const float* __restrict__ b3,  const float* __restrict__ b4,
    const float* __restrict__ b5,  const float* __restrict__ b7,
    const float* __restrict__ w6,  const float* __restrict__ b6,
    const float* __restrict__ w8,  const float* __restrict__ b8,
    const u16* __restrict__ wsz, float* __restrict__ out, int B) {

    __shared__ u16 pool[H_OFF + 96 * HS];   // 32448 u16 = 64896 B

    const int t    = threadIdx.x;
    const int lane = t & 63;
    const int wave = t >> 6;     // 0..7
    const int lr   = lane & 15;
    const int lg   = lane >> 4;
    const int wg   = blockIdx.x;

    // ---- Stage raw activations into LDS (coalesced) ----
    const int STG = H_OFF;       // transient; dead before first h write
    for (int i = t; i < 1760; i += 512) {             // obs 32x55 -> stride 56
        int b = i / 55, c = i - b * 55;
        pool[STG + b * 56 + c] = f2b(obs[wg * 1760 + i]);
    }
    for (int i = t; i < 288; i += 512) {              // ag -> stride 10
        int b = i / 9, c = i - b * 9;
        pool[STG + 1792 + b * 10 + c] = f2b(ag[wg * 288 + i]);
    }
    for (int i = t; i < 288; i += 512) {              // g
        int b = i / 9, c = i - b * 9;
        pool[STG + 2112 + b * 10 + c] = f2b(g[wg * 288 + i]);
    }
    if (t < 128)                                      // act 32x4
        pool[STG + 2432 + t] = f2b(act[wg * 128 + t]);
    for (int i = t; i < 288; i += 512) {              // anchor kept fp32!
        int b = i / 9, c = i - b * 9;
        ((u32*)pool)[(STG + 2560) / 2 + b * 10 + c] = __float_as_uint(anchor[wg * 288 + i]);
    }
    __syncthreads();

    // ---- Build pair inputs (96 rows x 54, zero-pad to 64) from LDS ----
    if (t < 96) {
        const int O1[3] = {0, 0, 1}, O2[3] = {1, 2, 2};
        const int JA[3] = {3, 4, 6}, KA[3] = {5, 7, 8};
        int p = t / 32, bl = t % 32;
        int j = JA[p], k = KA[p];
        float aj = __uint_as_float(((u32*)pool)[(STG + 2560) / 2 + bl * 10 + j]);
        float ak = __uint_as_float(((u32*)pool)[(STG + 2560) / 2 + bl * 10 + k]);
        bool sel = (aj - ak) >= 0.0f;
        int bit2 = sel ? j : k;
        int oi = sel ? O1[p] : O2[p];
        int oj = sel ? O2[p] : O1[p];
        u16* row = &pool[t * 72];
        row[0] = pool[STG + 1792 + bl * 10 + p];
        row[1] = pool[STG + 1792 + bl * 10 + bit2];
        row[2] = pool[STG + 2112 + bl * 10 + p];
        row[3] = pool[STG + 2112 + bl * 10 + bit2];
        for (int c = 0; c < 10; ++c) row[4 + c] = pool[STG + bl * 56 + c];
        const u16 ONE = 0x3F80;
        row[14] = (oi == 0) ? ONE : 0; row[15] = (oi == 1) ? ONE : 0; row[16] = (oi == 2) ? ONE : 0;
        for (int c = 0; c < 15; ++c) row[17 + c] = pool[STG + bl * 56 + 10 + 15 * oi + c];
        row[32] = (oj == 0) ? ONE : 0; row[33] = (oj == 1) ? ONE : 0; row[34] = (oj == 2) ? ONE : 0;
        for (int c = 0; c < 15; ++c) row[35 + c] = pool[STG + bl * 56 + 10 + 15 * oj + c];
        for (int c = 0; c < 4; ++c)  row[50 + c] = pool[STG + 2432 + bl * 4 + c];
        for (int c = 54; c < 64; ++c) row[c] = 0;
    }
    __syncthreads();

    f4  sacc[2][2];      // net1 (S2) pair-sums, fp32
    u32 s1p[2][2][2];    // net0 (S1) pair-sums, packed bf16

    // ---- Phi networks (net 0: w1/w2, net 1: w3/w4) ----
    for (int net = 0; net < 2; ++net) {
        const u16* Wl1 = wsz + (net ? 16384 : 0);
        const u16* Wl2 = wsz + 32768 + (net ? 65536 : 0);
        const float* bl1 = net ? b3 : b1;
        const float* bl2 = net ? b4 : b2;

        // Layer 1: (96 x 64) @ (64 x 256)
        f4 acc[6][2];
        #pragma unroll
        for (int rt = 0; rt < 6; ++rt)
            #pragma unroll
            for (int c = 0; c < 2; ++c) acc[rt][c] = (f4){0.f, 0.f, 0.f, 0.f};
        #pragma unroll
        for (int kt = 0; kt < 2; ++kt) {
            bf8 bfr[2];
            #pragma unroll
            for (int c = 0; c < 2; ++c)
                bfr[c] = *(const bf8*)(Wl1 + (size_t)(((kt * 16 + wave * 2 + c) * 64 + lane) * 8));
            #pragma unroll
            for (int rt = 0; rt < 6; ++rt) {
                bf8 afr = *(const bf8*)(&pool[(rt * 16 + lr) * 72 + kt * 32 + lg * 8]);
                #pragma unroll
                for (int c = 0; c < 2; ++c)
                    acc[rt][c] = __builtin_amdgcn_mfma_f32_16x16x32_bf16(afr, bfr[c], acc[rt][c], 0, 0, 0);
            }
        }
        #pragma unroll
        for (int c = 0; c < 2; ++c) {
            float bias = bl1[(wave * 2 + c) * 16 + lr];
            #pragma unroll
            for (int rt = 0; rt < 6; ++rt) {
                u32 p01 = pk2(fmaxf(acc[rt][c][0] + bias, 0.f), fmaxf(acc[rt][c][1] + bias, 0.f));
                u32 p23 = pk2(fmaxf(acc[rt][c][2] + bias, 0.f), fmaxf(acc[rt][c][3] + bias, 0.f));
                int base = H_OFF + (rt * 16 + lg * 4) * HS + (wave * 2 + c) * 16 + lr;
                pool[base]          = (u16)p01;
                pool[base + HS]     = (u16)(p01 >> 16);
                pool[base + 2 * HS] = (u16)p23;
                pool[base + 3 * HS] = (u16)(p23 >> 16);
            }
        }
        __syncthreads();

        // Layer 2: (96 x 256) @ (256 x 256), relu, pair-sum
        f4 acc2[6][2];
        #pragma unroll
        for (int rt = 0; rt < 6; ++rt)
            #pragma unroll
            for (int c = 0; c < 2; ++c) acc2[rt][c] = (f4){0.f, 0.f, 0.f, 0.f};
        #pragma unroll
        for (int ks = 0; ks < 8; ++ks) {
            bf8 bfr[2];
            #pragma unroll
            for (int c = 0; c < 2; ++c)
                bfr[c] = *(const bf8*)(Wl2 + (size_t)(((ks * 16 + wave * 2 + c) * 64 + lane) * 8));
            #pragma unroll
            for (int rt = 0; rt < 6; ++rt) {
                bf8 afr = *(const bf8*)(&pool[H_OFF + (rt * 16 + lr) * HS + ks * 32 + lg * 8]);
                #pragma unroll
                for (int c = 0; c < 2; ++c)
                    acc2[rt][c] = __builtin_amdgcn_mfma_f32_16x16x32_bf16(afr, bfr[c], acc2[rt][c], 0, 0, 0);
            }
        }
        #pragma unroll
        for (int c = 0; c < 2; ++c) {
            float bias = bl2[(wave * 2 + c) * 16 + lr];
            #pragma unroll
            for (int s = 0; s < 2; ++s) {
                f4 sv = (f4){0.f, 0.f, 0.f, 0.f};
                #pragma unroll
                for (int p = 0; p < 3; ++p)
                    #pragma unroll
                    for (int r = 0; r < 4; ++r)
                        sv[r] += fmaxf(acc2[p * 2 + s][c][r] + bias, 0.f);
                if (net == 0) {
                    s1p[s][c][0] = pk2(sv[0], sv[1]);
                    s1p[s][c][1] = pk2(sv[2], sv[3]);
                } else {
                    sacc[s][c] = sv;
                }
            }
        }
        __syncthreads();  // H reads done before next net overwrites H
    }

    // ---- Write S1 (h rows 0..31), S2 (rows 32..63) ----
    #pragma unroll
    for (int s = 0; s < 2; ++s)
        #pragma unroll
        for (int c = 0; c < 2; ++c) {
            int col = (wave * 2 + c) * 16 + lr;
            u32 a01 = pk2(sacc[s][c][0], sacc[s][c][1]);
            u32 a23 = pk2(sacc[s][c][2], sacc[s][c][3]);
            int base = H_OFF + (s * 16 + lg * 4) * HS + col;
            pool[base]                 = (u16)s1p[s][c][0];
            pool[base + HS]            = (u16)(s1p[s][c][0] >> 16);
            pool[base + 2 * HS]        = (u16)s1p[s][c][1];
            pool[base + 3 * HS]        = (u16)(s1p[s][c][1] >> 16);
            pool[base + S2O]           = (u16)a01;
            pool[base + S2O + HS]      = (u16)(a01 >> 16);
            pool[base + S2O + 2 * HS]  = (u16)a23;
            pool[base + S2O + 3 * HS]  = (u16)(a23 >> 16);
        }
    __syncthreads();

    // ---- Rho hidden layers, both nets in one MFMA phase ----
    {
        const u16* W5 = wsz + 163840;
        const u16* W7 = wsz + 229376;
        f4 racc[4][2];
        #pragma unroll
        for (int rt = 0; rt < 4; ++rt)
            #pragma unroll
            for (int c = 0; c < 2; ++c) racc[rt][c] = (f4){0.f, 0.f, 0.f, 0.f};
        #pragma unroll
        for (int ks = 0; ks < 8; ++ks) {
            bf8 bfr5[2], bfr7[2];
            #pragma unroll
            for (int c = 0; c < 2; ++c) {
                size_t off = (size_t)(((ks * 16 + wave * 2 + c) * 64 + lane) * 8);
                bfr5[c] = *(const bf8*)(W5 + off);
                bfr7[c] = *(const bf8*)(W7 + off);
            }
            #pragma unroll
            for (int rt = 0; rt < 2; ++rt) {
                bf8 a1 = *(const bf8*)(&pool[H_OFF + (rt * 16 + lr) * HS + ks * 32 + lg * 8]);
                bf8 a2 = *(const bf8*)(&pool[H_OFF + S2O + (rt * 16 + lr) * HS + ks * 32 + lg * 8]);
                #pragma unroll
                for (int c = 0; c < 2; ++c) {
                    racc[rt][c]     = __builtin_amdgcn_mfma_f32_16x16x32_bf16(a1, bfr5[c], racc[rt][c], 0, 0, 0);
                    racc[2 + rt][c] = __builtin_amdgcn_mfma_f32_16x16x32_bf16(a2, bfr7[c], racc[2 + rt][c], 0, 0, 0);
                }
            }
        }
        // net0 epilogue -> RH0 (h rows 64..95)
        #pragma unroll
        for (int c = 0; c < 2; ++c) {
            float bias = b5[(wave * 2 + c) * 16 + lr];
            #pragma unroll
            for (int rt = 0; rt < 2; ++rt) {
                u32 p01 = pk2(fmaxf(racc[rt][c][0] + bias, 0.f), fmaxf(racc[rt][c][1] + bias, 0.f));
                u32 p23 = pk2(fmaxf(racc[rt][c][2] + bias, 0.f), fmaxf(racc[rt][c][3] + bias, 0.f));
                int base = H_OFF + RH0O + (rt * 16 + lg * 4) * HS + (wave * 2 + c) * 16 + lr;
                pool[base]          = (u16)p01;
                pool[base + HS]     = (u16)(p01 >> 16);
                pool[base + 2 * HS] = (u16)p23;
                pool[base + 3 * HS] = (u16)(p23 >> 16);
            }
        }
        __syncthreads();   // all S1 reads done before net1 overwrites it
        // net1 epilogue -> RH1 (over consumed S1, h rows 0..31)
        #pragma unroll
        for (int c = 0; c < 2; ++c) {
            float bias = b7[(wave * 2 + c) * 16 + lr];
            #pragma unroll
            for (int rt = 0; rt < 2; ++rt) {
                u32 p01 = pk2(fmaxf(racc[2 + rt][c][0] + bias, 0.f), fmaxf(racc[2 + rt][c][1] + bias, 0.f));
                u32 p23 = pk2(fmaxf(racc[2 + rt][c][2] + bias, 0.f), fmaxf(racc[2 + rt][c][3] + bias, 0.f));
                int base = H_OFF + (rt * 16 + lg * 4) * HS + (wave * 2 + c) * 16 + lr;
                pool[base]          = (u16)p01;
                pool[base + HS]     = (u16)(p01 >> 16);
                pool[base + 2 * HS] = (u16)p23;
                pool[base + 3 * HS] = (u16)(p23 >> 16);
            }
        }
        __syncthreads();
    }

    // ---- Final dots, split-K over 8 waves: q = rhoH @ w6 + b6. FP32 OUT ----
    {
        int net = lane >> 5, r = lane & 31;
        int hoff = net ? H_OFF : H_OFF + RH0O;
        const float* wv = net ? w8 : w6;
        float s = 0.f;
        int base = hoff + r * HS + wave * 32;
        #pragma unroll
        for (int it = 0; it < 8; ++it) {
            uint2 two = *(const uint2*)&pool[base + it * 4];
            float4 wq = *(const float4*)(wv + wave * 32 + it * 4);
            s += __uint_as_float(two.x << 16)          * wq.x;
            s += __uint_as_float(two.x & 0xffff0000u)  * wq.y;
            s += __uint_as_float(two.y << 16)          * wq.z;
            s += __uint_as_float(two.y & 0xffff0000u)  * wq.w;
        }
        ((u32*)pool)[t] = __float_as_uint(s);   // partials in dead inp region
    }
    __syncthreads();
    if (t < 64) {
        int net = t >> 5, r = t & 31;
        float qv = net ? b8[0] : b6[0];
        #pragma unroll
        for (int p = 0; p < 8; ++p)
            qv += __uint_as_float(((u32*)pool)[p * 64 + t]);
        out[net * B + wg * 32 + r] = qv;
    }
}

extern "C" void kernel_launch(void* const* d_in, const int* in_sizes, int n_in,
                              void* d_out, int out_size, void* d_ws, size_t ws_size,
                              hipStream_t stream) {
    const float* obs = (const float*)d_in[0];
    const float* ag  = (const float*)d_in[1];
    const float* g   = (const float*)d_in[2];
    const float* anc = (const float*)d_in[3];
    const float* act = (const float*)d_in[4];
    const float* w1  = (const float*)d_in[5];
    const float* b1  = (const float*)d_in[6];
    const float* w2  = (const float*)d_in[7];
    const float* b2  = (const float*)d_in[8];
    const float* w3  = (const float*)d_in[9];
    const float* b3  = (const float*)d_in[10];
    const float* w4  = (const float*)d_in[11];
    const float* b4  = (const float*)d_in[12];
    const float* w5  = (const float*)d_in[13];
    const float* b5  = (const float*)d_in[14];
    const float* w6  = (const float*)d_in[15];
    const float* b6  = (const float*)d_in[16];
    const float* w7  = (const float*)d_in[17];
    const float* b7  = (const float*)d_in[18];
    const float* w8  = (const float*)d_in[19];
    const float* b8  = (const float*)d_in[20];
    u16* ws    = (u16*)d_ws;
    float* out = (float*)d_out;
    int B = in_sizes[0] / 55;

    swz_all<<<36, 256, 0, stream>>>(w1, w3, w2, w4, w5, w7, ws);
    critic_kernel<<<(B + 31) / 32, 512, 0, stream>>>(obs, ag, g, anc, act,
                                                     b1, b2, b3, b4, b5, b7,
                                                     w6, b6, w8, b8, ws, out, B);
}

// Round 9
// 201.190 us; speedup vs baseline: 1.1333x; 1.1333x over previous
//
#include <hip/hip_runtime.h>
#include <hip/hip_bf16.h>

typedef unsigned short u16;
typedef unsigned int   u32;

using bf8 = __attribute__((ext_vector_type(8))) __bf16;
using f4  = __attribute__((ext_vector_type(4))) float;

__device__ __forceinline__ float b2f(u16 u) {
    union { u32 i; float f; } v; v.i = ((u32)u) << 16; return v.f;
}
__device__ __forceinline__ u16 f2b(float f) {
    union { float f; u32 i; } v; v.f = f;
    u32 x = v.i;
    x += 0x7fffu + ((x >> 16) & 1u);   // RNE
    return (u16)(x >> 16);
}
// Packed fp32x2 -> bf16x2 (low = first arg).
__device__ __forceinline__ u32 pk2(float lo, float hi) {
    union { __hip_bfloat162 h; u32 u; } v;
    v.h = __float22bfloat162_rn(make_float2(lo, hi));
    return v.u;
}

// ---------------------------------------------------------------------------
// Weight swizzle (verified layout — unchanged; frags now used as A-operands):
// dst[((kt*16+ct)*64+lane)*8+j] = bf16(W[kt*32+(lane>>4)*8+j][ct*16+(lane&15)])
// ---------------------------------------------------------------------------
__global__ void swz_all(const float* __restrict__ w1, const float* __restrict__ w3,
                        const float* __restrict__ w2, const float* __restrict__ w4,
                        const float* __restrict__ w5, const float* __restrict__ w7,
                        u16* __restrict__ ws) {
    __shared__ u16 slab[32 * 270];
    int b = blockIdx.x, t = threadIdx.x;
    const float* src; u16* dst; int kmax, kt;
    if      (b <  2) { src = w1; dst = ws;          kmax = 54;  kt = b;      }
    else if (b <  4) { src = w3; dst = ws + 16384;  kmax = 54;  kt = b - 2;  }
    else if (b < 12) { src = w2; dst = ws + 32768;  kmax = 256; kt = b - 4;  }
    else if (b < 20) { src = w4; dst = ws + 98304;  kmax = 256; kt = b - 12; }
    else if (b < 28) { src = w5; dst = ws + 163840; kmax = 256; kt = b - 20; }
    else             { src = w7; dst = ws + 229376; kmax = 256; kt = b - 28; }

    #pragma unroll
    for (int it = 0; it < 8; ++it) {
        int flat = it * 1024 + t * 4;
        int row = flat >> 8, col = flat & 255;
        int k = kt * 32 + row;
        float4 v = make_float4(0.f, 0.f, 0.f, 0.f);
        if (k < kmax) v = *(const float4*)(src + k * 256 + col);
        u32* sp = (u32*)&slab[row * 270 + col];
        sp[0] = pk2(v.x, v.y);
        sp[1] = pk2(v.z, v.w);
    }
    __syncthreads();

    int lane = t & 63, wave = t >> 6, lr = lane & 15, kg = lane >> 4;
    #pragma unroll
    for (int i = 0; i < 4; ++i) {
        int ct = wave * 4 + i;
        u16 v[8];
        #pragma unroll
        for (int j = 0; j < 8; ++j)
            v[j] = slab[(kg * 8 + j) * 270 + ct * 16 + lr];
        uint4 o;
        o.x = (u32)v[0] | ((u32)v[1] << 16);
        o.y = (u32)v[2] | ((u32)v[3] << 16);
        o.z = (u32)v[4] | ((u32)v[5] << 16);
        o.w = (u32)v[6] | ((u32)v[7] << 16);
        *(uint4*)(dst + (size_t)(((kt * 16 + ct) * 64 + lane) * 8)) = o;
    }
}

// ---------------------------------------------------------------------------
// Fused critic, operand-swapped MFMA: A = swizzled weights (global/L2),
// B = activations (LDS b128 row-major). C/D per lane = (batch=lane&15,
// hidden=lg*4+reg) -> row-major-contiguous -> b64 epilogue writes.
// One WG = 32 batch rows, 256 threads, 4 waves, 4 hidden-tiles/wave.
// LDS pool (u16): inp [0,6912) 96x72; h [6912,+96*264) stride 264.
// h reuse: S1 rows 0..31, S2 rows 32..63, RH0 rows 64..95, RH1 over S1.
// ---------------------------------------------------------------------------
#define HS    264
#define H_OFF 6912
#define S2O   (32 * HS)
#define RH0O  (64 * HS)

__global__ __launch_bounds__(256, 2) void critic_kernel(
    const float* __restrict__ obs, const float* __restrict__ ag,
    const float* __restrict__ g,   const float* __restrict__ anchor,
    const float* __restrict__ act,
    const float* __restrict__ b1,  const float* __restrict__ b2,
    const float* __restrict__ b3,  const float* __restrict__ b4,
    const float* __restrict__ b5,  const float* __restrict__ b7,
    const float* __restrict__ w6,  const float* __restrict__ b6,
    const float* __restrict__ w8,  const float* __restrict__ b8,
    const u16* __restrict__ wsz, float* __restrict__ out, int B) {

    __shared__ u16 pool[H_OFF + 96 * HS];   // 32256 u16 = 64512 B

    const int t    = threadIdx.x;
    const int lane = t & 63;
    const int wave = t >> 6;
    const int lr   = lane & 15;
    const int lg   = lane >> 4;
    const int wg   = blockIdx.x;

    // ---- Gather: build pair inputs (96 rows x 54, pad to 64), direct global
    if (t < 96) {
        const int O1[3] = {0, 0, 1}, O2[3] = {1, 2, 2};
        const int JA[3] = {3, 4, 6}, KA[3] = {5, 7, 8};
        int p = t / 32, bl = t % 32;
        int b = wg * 32 + bl;
        int j = JA[p], k = KA[p];
        bool sel = (anchor[b * 9 + j] - anchor[b * 9 + k]) >= 0.0f;
        int bit2 = sel ? j : k;
        int oi = sel ? O1[p] : O2[p];
        int oj = sel ? O2[p] : O1[p];
        u16* row = &pool[t * 72];
        row[0] = f2b(ag[b * 9 + p]);
        row[1] = f2b(ag[b * 9 + bit2]);
        row[2] = f2b(g[b * 9 + p]);
        row[3] = f2b(g[b * 9 + bit2]);
        for (int c = 0; c < 10; ++c) row[4 + c] = f2b(obs[b * 55 + c]);
        const u16 ONE = 0x3F80;
        row[14] = (oi == 0) ? ONE : 0; row[15] = (oi == 1) ? ONE : 0; row[16] = (oi == 2) ? ONE : 0;
        for (int c = 0; c < 15; ++c) row[17 + c] = f2b(obs[b * 55 + 10 + 15 * oi + c]);
        row[32] = (oj == 0) ? ONE : 0; row[33] = (oj == 1) ? ONE : 0; row[34] = (oj == 2) ? ONE : 0;
        for (int c = 0; c < 15; ++c) row[35 + c] = f2b(obs[b * 55 + 10 + 15 * oj + c]);
        for (int c = 0; c < 4; ++c)  row[50 + c] = f2b(act[b * 4 + c]);
        for (int c = 54; c < 64; ++c) row[c] = 0;
    }
    __syncthreads();

    u32 s1w[2][4][2];    // net0 pair-sums, packed bf16 pairs (hidden-adjacent)
    u32 s2w[2][4][2];    // net1 pair-sums

    // ---- Phi networks (net 0: w1/w2, net 1: w3/w4) ----
    for (int net = 0; net < 2; ++net) {
        const u16* Wl1 = wsz + (net ? 16384 : 0);
        const u16* Wl2 = wsz + 32768 + (net ? 65536 : 0);
        const float* bl1 = net ? b3 : b1;
        const float* bl2 = net ? b4 : b2;

        // Layer 1: A=W1^T frags, B=inp rows. D = x1^T per-lane layout.
        f4 acc[6][4];
        #pragma unroll
        for (int rt = 0; rt < 6; ++rt)
            #pragma unroll
            for (int c = 0; c < 4; ++c) acc[rt][c] = (f4){0.f, 0.f, 0.f, 0.f};
        #pragma unroll
        for (int kt = 0; kt < 2; ++kt) {
            bf8 wfr[4];
            #pragma unroll
            for (int c = 0; c < 4; ++c)
                wfr[c] = *(const bf8*)(Wl1 + (size_t)(((kt * 16 + wave * 4 + c) * 64 + lane) * 8));
            #pragma unroll
            for (int rt = 0; rt < 6; ++rt) {
                bf8 xfr = *(const bf8*)(&pool[(rt * 16 + lr) * 72 + kt * 32 + lg * 8]);
                #pragma unroll
                for (int c = 0; c < 4; ++c)
                    acc[rt][c] = __builtin_amdgcn_mfma_f32_16x16x32_bf16(wfr[c], xfr, acc[rt][c], 0, 0, 0);
            }
        }
        #pragma unroll
        for (int c = 0; c < 4; ++c) {
            float4 bv = *(const float4*)(bl1 + (wave * 4 + c) * 16 + lg * 4);
            #pragma unroll
            for (int rt = 0; rt < 6; ++rt) {
                uint2 w;
                w.x = pk2(fmaxf(acc[rt][c][0] + bv.x, 0.f), fmaxf(acc[rt][c][1] + bv.y, 0.f));
                w.y = pk2(fmaxf(acc[rt][c][2] + bv.z, 0.f), fmaxf(acc[rt][c][3] + bv.w, 0.f));
                *(uint2*)&pool[H_OFF + (rt * 16 + lr) * HS + (wave * 4 + c) * 16 + lg * 4] = w;
            }
        }
        __syncthreads();

        // Layer 2: A=W2^T frags, B=h rows. Relu + pair-sum into regs.
        f4 acc2[6][4];
        #pragma unroll
        for (int rt = 0; rt < 6; ++rt)
            #pragma unroll
            for (int c = 0; c < 4; ++c) acc2[rt][c] = (f4){0.f, 0.f, 0.f, 0.f};
        #pragma unroll
        for (int ks = 0; ks < 8; ++ks) {
            bf8 wfr[4];
            #pragma unroll
            for (int c = 0; c < 4; ++c)
                wfr[c] = *(const bf8*)(Wl2 + (size_t)(((ks * 16 + wave * 4 + c) * 64 + lane) * 8));
            #pragma unroll
            for (int rt = 0; rt < 6; ++rt) {
                bf8 hfr = *(const bf8*)(&pool[H_OFF + (rt * 16 + lr) * HS + ks * 32 + lg * 8]);
                #pragma unroll
                for (int c = 0; c < 4; ++c)
                    acc2[rt][c] = __builtin_amdgcn_mfma_f32_16x16x32_bf16(wfr[c], hfr, acc2[rt][c], 0, 0, 0);
            }
        }
        #pragma unroll
        for (int c = 0; c < 4; ++c) {
            float4 bv = *(const float4*)(bl2 + (wave * 4 + c) * 16 + lg * 4);
            #pragma unroll
            for (int s = 0; s < 2; ++s) {
                f4 sv = (f4){0.f, 0.f, 0.f, 0.f};
                #pragma unroll
                for (int p = 0; p < 3; ++p) {
                    sv[0] += fmaxf(acc2[p * 2 + s][c][0] + bv.x, 0.f);
                    sv[1] += fmaxf(acc2[p * 2 + s][c][1] + bv.y, 0.f);
                    sv[2] += fmaxf(acc2[p * 2 + s][c][2] + bv.z, 0.f);
                    sv[3] += fmaxf(acc2[p * 2 + s][c][3] + bv.w, 0.f);
                }
                if (net == 0) {
                    s1w[s][c][0] = pk2(sv[0], sv[1]);
                    s1w[s][c][1] = pk2(sv[2], sv[3]);
                } else {
                    s2w[s][c][0] = pk2(sv[0], sv[1]);
                    s2w[s][c][1] = pk2(sv[2], sv[3]);
                }
            }
        }
        __syncthreads();  // h reads done before next net overwrites h
    }

    // ---- Write S1 (rows 0..31), S2 (rows 32..63): one b64 each ----
    #pragma unroll
    for (int s = 0; s < 2; ++s)
        #pragma unroll
        for (int c = 0; c < 4; ++c) {
            int base = H_OFF + (s * 16 + lr) * HS + (wave * 4 + c) * 16 + lg * 4;
            *(uint2*)&pool[base]       = *(uint2*)&s1w[s][c][0];
            *(uint2*)&pool[base + S2O] = *(uint2*)&s2w[s][c][0];
        }
    __syncthreads();

    // ---- Rho hidden layers, both nets in one MFMA phase ----
    {
        const u16* W5 = wsz + 163840;
        const u16* W7 = wsz + 229376;
        f4 racc[4][4];
        #pragma unroll
        for (int rt = 0; rt < 4; ++rt)
            #pragma unroll
            for (int c = 0; c < 4; ++c) racc[rt][c] = (f4){0.f, 0.f, 0.f, 0.f};
        #pragma unroll
        for (int ks = 0; ks < 8; ++ks) {
            bf8 w5f[4], w7f[4];
            #pragma unroll
            for (int c = 0; c < 4; ++c) {
                size_t off = (size_t)(((ks * 16 + wave * 4 + c) * 64 + lane) * 8);
                w5f[c] = *(const bf8*)(W5 + off);
                w7f[c] = *(const bf8*)(W7 + off);
            }
            #pragma unroll
            for (int rt = 0; rt < 2; ++rt) {
                bf8 s1f = *(const bf8*)(&pool[H_OFF + (rt * 16 + lr) * HS + ks * 32 + lg * 8]);
                bf8 s2f = *(const bf8*)(&pool[H_OFF + S2O + (rt * 16 + lr) * HS + ks * 32 + lg * 8]);
                #pragma unroll
                for (int c = 0; c < 4; ++c) {
                    racc[rt][c]     = __builtin_amdgcn_mfma_f32_16x16x32_bf16(w5f[c], s1f, racc[rt][c], 0, 0, 0);
                    racc[2 + rt][c] = __builtin_amdgcn_mfma_f32_16x16x32_bf16(w7f[c], s2f, racc[2 + rt][c], 0, 0, 0);
                }
            }
        }
        // net0 epilogue -> RH0 (rows 64..95; disjoint from S reads -> no barrier)
        #pragma unroll
        for (int c = 0; c < 4; ++c) {
            float4 bv = *(const float4*)(b5 + (wave * 4 + c) * 16 + lg * 4);
            #pragma unroll
            for (int rt = 0; rt < 2; ++rt) {
                uint2 w;
                w.x = pk2(fmaxf(racc[rt][c][0] + bv.x, 0.f), fmaxf(racc[rt][c][1] + bv.y, 0.f));
                w.y = pk2(fmaxf(racc[rt][c][2] + bv.z, 0.f), fmaxf(racc[rt][c][3] + bv.w, 0.f));
                *(uint2*)&pool[H_OFF + RH0O + (rt * 16 + lr) * HS + (wave * 4 + c) * 16 + lg * 4] = w;
            }
        }
        __syncthreads();   // all S1 reads done before net1 overwrites it
        // net1 epilogue -> RH1 (over consumed S1, rows 0..31)
        #pragma unroll
        for (int c = 0; c < 4; ++c) {
            float4 bv = *(const float4*)(b7 + (wave * 4 + c) * 16 + lg * 4);
            #pragma unroll
            for (int rt = 0; rt < 2; ++rt) {
                uint2 w;
                w.x = pk2(fmaxf(racc[2 + rt][c][0] + bv.x, 0.f), fmaxf(racc[2 + rt][c][1] + bv.y, 0.f));
                w.y = pk2(fmaxf(racc[2 + rt][c][2] + bv.z, 0.f), fmaxf(racc[2 + rt][c][3] + bv.w, 0.f));
                *(uint2*)&pool[H_OFF + (rt * 16 + lr) * HS + (wave * 4 + c) * 16 + lg * 4] = w;
            }
        }
        __syncthreads();
    }

    // ---- Final dots, split-K over 4 waves: q = rhoH @ w6 + b6. FP32 OUT ----
    {
        int net = lane >> 5, r = lane & 31;
        int hoff = net ? H_OFF : H_OFF + RH0O;
        const float* wv = net ? w8 : w6;
        float s = 0.f;
        int base = hoff + r * HS + wave * 64;
        #pragma unroll
        for (int it = 0; it < 16; ++it) {
            uint2 two = *(const uint2*)&pool[base + it * 4];
            float4 wq = *(const float4*)(wv + wave * 64 + it * 4);
            s += __uint_as_float(two.x << 16)          * wq.x;
            s += __uint_as_float(two.x & 0xffff0000u)  * wq.y;
            s += __uint_as_float(two.y << 16)          * wq.z;
            s += __uint_as_float(two.y & 0xffff0000u)  * wq.w;
        }
        ((u32*)pool)[t] = __float_as_uint(s);   // partials in dead inp region
    }
    __syncthreads();
    if (t < 64) {
        int net = t >> 5, r = t & 31;
        float qv = net ? b8[0] : b6[0];
        #pragma unroll
        for (int p = 0; p < 4; ++p)
            qv += __uint_as_float(((u32*)pool)[p * 64 + t]);
        out[net * B + wg * 32 + r] = qv;
    }
}

extern "C" void kernel_launch(void* const* d_in, const int* in_sizes, int n_in,
                              void* d_out, int out_size, void* d_ws, size_t ws_size,
                              hipStream_t stream) {
    const float* obs = (const float*)d_in[0];
    const float* ag  = (const float*)d_in[1];
    const float* g   = (const float*)d_in[2];
    const float* anc = (const float*)d_in[3];
    const float* act = (const float*)d_in[4];
    const float* w1  = (const float*)d_in[5];
    const float* b1  = (const float*)d_in[6];
    const float* w2  = (const float*)d_in[7];
    const float* b2  = (const float*)d_in[8];
    const float* w3  = (const float*)d_in[9];
    const float* b3  = (const float*)d_in[10];
    const float* w4  = (const float*)d_in[11];
    const float* b4  = (const float*)d_in[12];
    const float* w5  = (const float*)d_in[13];
    const float* b5  = (const float*)d_in[14];
    const float* w6  = (const float*)d_in[15];
    const float* b6  = (const float*)d_in[16];
    const float* w7  = (const float*)d_in[17];
    const float* b7  = (const float*)d_in[18];
    const float* w8  = (const float*)d_in[19];
    const float* b8  = (const float*)d_in[20];
    u16* ws    = (u16*)d_ws;
    float* out = (float*)d_out;
    int B = in_sizes[0] / 55;

    swz_all<<<36, 256, 0, stream>>>(w1, w3, w2, w4, w5, w7, ws);
    critic_kernel<<<(B + 31) / 32, 256, 0, stream>>>(obs, ag, g, anc, act,
                                                     b1, b2, b3, b4, b5, b7,
                                                     w6, b6, w8, b8, ws, out, B);
}